// Round 1
// baseline (249.842 us; speedup 1.0000x reference)
//
#include <hip/hip_runtime.h>

// OrthogonalLayer2D: x (8,32,128,32,32) f32.
// Reshape to (N=8, MC=4096, D=1024); for each mc, Gram-Schmidt the 8 vectors
// of length 1024 (classical GS, coeffs from original v), normalize, NaN->0.
// Output layout identical to input layout.

#define MC   4096
#define DIM  1024
#define NV   8
#define TPB  256

__global__ __launch_bounds__(TPB) void gs_kernel(const float* __restrict__ x,
                                                 float* __restrict__ out) {
    const int mc   = blockIdx.x;
    const int t    = threadIdx.x;
    const int lane = t & 63;
    const int wave = t >> 6;

    __shared__ float red[4][NV];

    const size_t strideN = (size_t)MC * DIM;            // 4,194,304 floats
    const size_t base    = (size_t)mc * DIM + (size_t)t * 4;

    // Load: 8 vectors x 4 elements per thread, coalesced float4.
    float v[NV][4];
#pragma unroll
    for (int n = 0; n < NV; ++n) {
        const float4 f = *reinterpret_cast<const float4*>(x + n * strideN + base);
        v[n][0] = f.x; v[n][1] = f.y; v[n][2] = f.z; v[n][3] = f.w;
    }

    // In-register classical Gram-Schmidt; v[i] becomes basis vector i.
#pragma unroll
    for (int i = 0; i < NV; ++i) {
        // --- coefficients c[j] = <v_i, b_j> for j < i (batched block reduce) ---
        if (i > 0) {
            float c[NV];
#pragma unroll
            for (int j = 0; j < NV; ++j) {
                if (j >= i) break;
                float s = v[i][0] * v[j][0] + v[i][1] * v[j][1]
                        + v[i][2] * v[j][2] + v[i][3] * v[j][3];
#pragma unroll
                for (int off = 32; off >= 1; off >>= 1) s += __shfl_xor(s, off, 64);
                if (lane == 0) red[wave][j] = s;
            }
            __syncthreads();
#pragma unroll
            for (int j = 0; j < NV; ++j) {
                if (j >= i) break;
                c[j] = red[0][j] + red[1][j] + red[2][j] + red[3][j];
            }
            __syncthreads();   // red reusable
#pragma unroll
            for (int j = 0; j < NV; ++j) {
                if (j >= i) break;
#pragma unroll
                for (int e = 0; e < 4; ++e) v[i][e] -= c[j] * v[j][e];
            }
        }

        // --- normalize: w / ||w||, zero-vector -> 0 (matches NaN->0 rule) ---
        float s = v[i][0] * v[i][0] + v[i][1] * v[i][1]
                + v[i][2] * v[i][2] + v[i][3] * v[i][3];
#pragma unroll
        for (int off = 32; off >= 1; off >>= 1) s += __shfl_xor(s, off, 64);
        if (lane == 0) red[wave][0] = s;
        __syncthreads();
        const float n2 = red[0][0] + red[1][0] + red[2][0] + red[3][0];
        __syncthreads();
        const float rn = (n2 > 0.0f) ? rsqrtf(n2) : 0.0f;
#pragma unroll
        for (int e = 0; e < 4; ++e) v[i][e] *= rn;
    }

    // Store, coalesced float4, same layout as input.
#pragma unroll
    for (int n = 0; n < NV; ++n) {
        float4 f;
        f.x = v[n][0]; f.y = v[n][1]; f.z = v[n][2]; f.w = v[n][3];
        *reinterpret_cast<float4*>(out + n * strideN + base) = f;
    }
}

extern "C" void kernel_launch(void* const* d_in, const int* in_sizes, int n_in,
                              void* d_out, int out_size, void* d_ws, size_t ws_size,
                              hipStream_t stream) {
    const float* x = (const float*)d_in[0];
    float* out = (float*)d_out;
    gs_kernel<<<MC, TPB, 0, stream>>>(x, out);
}

// Round 2
// 244.630 us; speedup vs baseline: 1.0213x; 1.0213x over previous
//
#include <hip/hip_runtime.h>

// OrthogonalLayer2D via Cholesky-QR (algebraically == classical Gram-Schmidt):
//   x reshaped (N=8, MC=4096, D=1024). Per mc: G = V V^T (8x8), L = chol(G),
//   B = L^{-1} V  (forward substitution), row i normalized by 1/L[i][i].
// One 128-thread block per mc pair; 8 elems/thread in registers; ONE batched
// block-reduction round (36 independent values) instead of 16 serial rounds.

#define MC   4096
#define DIM  1024
#define NV   8
#define TPB  128          // 2 waves
#define E    8            // elems per thread; two coalesced float4 chunks
#define IDX(i,j) ((i)*((i)+1)/2+(j))   // packed lower-tri index, i >= j

__global__ __launch_bounds__(TPB) void gs_kernel(const float* __restrict__ x,
                                                 float* __restrict__ out) {
    const int mc   = blockIdx.x;
    const int t    = threadIdx.x;
    const int lane = t & 63;
    const int wave = t >> 6;

    __shared__ float red[2][36];

    const size_t strideN = (size_t)MC * DIM;
    const size_t base    = (size_t)mc * DIM;

    // Load: two half-chunks so every float4 load is lane-contiguous (1 KB/wave).
    float v[NV][E];
#pragma unroll
    for (int n = 0; n < NV; ++n) {
        const float4 a = *reinterpret_cast<const float4*>(x + n * strideN + base + (size_t)t * 4);
        const float4 b = *reinterpret_cast<const float4*>(x + n * strideN + base + 512 + (size_t)t * 4);
        v[n][0] = a.x; v[n][1] = a.y; v[n][2] = a.z; v[n][3] = a.w;
        v[n][4] = b.x; v[n][5] = b.y; v[n][6] = b.z; v[n][7] = b.w;
    }

    // 36 Gram partials (lower triangle incl. diagonal).
    float g[36];
#pragma unroll
    for (int i = 0; i < NV; ++i) {
#pragma unroll
        for (int j = 0; j <= i; ++j) {
            float s = 0.0f;
#pragma unroll
            for (int e = 0; e < E; ++e) s += v[i][e] * v[j][e];
            g[IDX(i, j)] = s;
        }
    }

    // Wave butterfly reduce — 36 independent chains, fully pipelined.
#pragma unroll
    for (int k = 0; k < 36; ++k) {
        float s = g[k];
#pragma unroll
        for (int off = 1; off < 64; off <<= 1) s += __shfl_xor(s, off, 64);
        g[k] = s;
    }

    // Cross-wave combine: lane 0 of each wave writes 9 float4s; one barrier.
    if (lane == 0) {
#pragma unroll
        for (int k = 0; k < 36; k += 4) {
            *reinterpret_cast<float4*>(&red[wave][k]) =
                make_float4(g[k], g[k + 1], g[k + 2], g[k + 3]);
        }
    }
    __syncthreads();
#pragma unroll
    for (int k = 0; k < 36; k += 4) {
        const float4 a = *reinterpret_cast<const float4*>(&red[0][k]);
        const float4 b = *reinterpret_cast<const float4*>(&red[1][k]);
        g[k + 0] = a.x + b.x; g[k + 1] = a.y + b.y;
        g[k + 2] = a.z + b.z; g[k + 3] = a.w + b.w;
    }

    // In-register 8x8 Cholesky: g becomes L (packed lower-tri). Uniform work.
    float rdiag[NV];   // 1/L[i][i], 0 if degenerate (replicates NaN->0 rule)
#pragma unroll
    for (int i = 0; i < NV; ++i) {
#pragma unroll
        for (int j = 0; j < i; ++j) {
            float s = g[IDX(i, j)];
#pragma unroll
            for (int p = 0; p < NV; ++p) {
                if (p >= j) break;
                s -= g[IDX(i, p)] * g[IDX(j, p)];
            }
            g[IDX(i, j)] = s * rdiag[j];
        }
        float d = g[IDX(i, i)];
#pragma unroll
        for (int p = 0; p < NV; ++p) {
            if (p >= i) break;
            d -= g[IDX(i, p)] * g[IDX(i, p)];
        }
        g[IDX(i, i)] = (d > 0.0f) ? sqrtf(d) : 0.0f;
        rdiag[i]     = (d > 0.0f) ? rsqrtf(d) : 0.0f;
    }

    // Forward substitution: v[i] <- (v[i] - sum_{j<i} L[i][j] * b[j]) / L[i][i].
#pragma unroll
    for (int i = 0; i < NV; ++i) {
#pragma unroll
        for (int j = 0; j < NV; ++j) {
            if (j >= i) break;
            const float lij = g[IDX(i, j)];
#pragma unroll
            for (int e = 0; e < E; ++e) v[i][e] -= lij * v[j][e];
        }
        const float r = rdiag[i];
#pragma unroll
        for (int e = 0; e < E; ++e) v[i][e] *= r;
    }

    // Store, same coalesced two-chunk pattern.
#pragma unroll
    for (int n = 0; n < NV; ++n) {
        *reinterpret_cast<float4*>(out + n * strideN + base + (size_t)t * 4) =
            make_float4(v[n][0], v[n][1], v[n][2], v[n][3]);
        *reinterpret_cast<float4*>(out + n * strideN + base + 512 + (size_t)t * 4) =
            make_float4(v[n][4], v[n][5], v[n][6], v[n][7]);
    }
}

extern "C" void kernel_launch(void* const* d_in, const int* in_sizes, int n_in,
                              void* d_out, int out_size, void* d_ws, size_t ws_size,
                              hipStream_t stream) {
    const float* x = (const float*)d_in[0];
    float* out = (float*)d_out;
    gs_kernel<<<MC, TPB, 0, stream>>>(x, out);
}